// Round 6
// baseline (524.067 us; speedup 1.0000x reference)
//
#include <hip/hip_runtime.h>
#include <math.h>

// ---------------------------------------------------------------------------
// DynamicAttention4 (B=32 L=256 S=T=64 H=768 Q=768 F=1024 OUT=768)
// q=query@Wq+bq; s_key=src@Ws+bs; t_key=trg@Wt+bt
// rel_key[b,t,s,:]=tanh(s_key[b,s,:]+t_key[b,t,:])   (never materialized)
// scores[b,l,ts]=q·rel_key/sqrt(768); softmax over ts=4096
// ctx[b,l,:]=sum_ts w*rel_key; out=relu([query,ctx]@Wo+bo)
//
// Round-5 == round-4 resubmit (GPU acquisition timed out; no data).
// ctx retiled m128 x n64 -> grid 768 blocks (3/CU, 12 waves/CU) to fix the
// occupancy/latency bound. s_key/t_key read direct from global (L1-resident).
// ---------------------------------------------------------------------------

typedef __attribute__((ext_vector_type(8))) short bf16x8;
typedef __attribute__((ext_vector_type(4))) float f32x4;

__device__ __forceinline__ unsigned short f2bf(float f) {
    union { float f; unsigned u; } x; x.f = f;
    unsigned u = x.u;
    return (unsigned short)((u + 0x7fffu + ((u >> 16) & 1u)) >> 16);
}
__device__ __forceinline__ float bf2f(unsigned short h) {
    union { unsigned u; float f; } x; x.u = (unsigned)h << 16;
    return x.f;
}
__device__ __forceinline__ float tanh_fast(float x) {
    float e = __expf(2.0f * x);
    return 1.0f - 2.0f * __builtin_amdgcn_rcpf(1.0f + e);
}
__device__ __forceinline__ void async_copy16(void* lds, const void* g) {
    __builtin_amdgcn_global_load_lds(
        (const __attribute__((address_space(1))) unsigned int*)g,
        (__attribute__((address_space(3))) unsigned int*)lds,
        16, 0, 0);
}

// ---------------------------------------------------------------------------
// Batched bf16 BT-GEMM: C[z][m,n] = sum_k A[z][m,k]*BT[z][n,k] (+bias,+relu)
// 128x128 tile, BK=32, 4 waves, 4x4 16x16x32 frags. Same k-map for A/B.
// ---------------------------------------------------------------------------
template<bool OUT_BF16, bool RELU>
__global__ __launch_bounds__(256, 2) void gemm_bt_kernel(
    const unsigned short* __restrict__ A, const unsigned short* __restrict__ BT,
    void* __restrict__ Cout, const float* __restrict__ bias,
    int M, int N, int K, int lda, int ldb, int ldc,
    long long sA, long long sB, long long sC)
{
    __shared__ unsigned short As[128 * 32];
    __shared__ unsigned short Bs[128 * 32];
    const int z = blockIdx.z;
    A  += (long long)z * sA;
    BT += (long long)z * sB;
    const int m0 = blockIdx.x * 128, n0 = blockIdx.y * 128;
    const int tid = threadIdx.x;
    const int lane = tid & 63, wid = tid >> 6;
    const int wr = wid >> 1, wc = wid & 1;
    const int r = lane & 15, g = lane >> 4;

    f32x4 acc[4][4] = {};

    for (int k0 = 0; k0 < K; k0 += 32) {
        __syncthreads();
        #pragma unroll
        for (int j = 0; j < 2; ++j) {
            int c = j * 256 + tid;
            int row = c >> 2, kc = (c & 3) * 8;
            async_copy16(&As[c * 8], A  + (size_t)(m0 + row) * lda + k0 + kc);
            async_copy16(&Bs[c * 8], BT + (size_t)(n0 + row) * ldb + k0 + kc);
        }
        asm volatile("s_waitcnt vmcnt(0)" ::: "memory");
        __syncthreads();

        bf16x8 af[4], bfr[4];
        #pragma unroll
        for (int m = 0; m < 4; ++m)
            af[m] = *(const bf16x8*)&As[(wr * 64 + m * 16 + r) * 32 + g * 8];
        #pragma unroll
        for (int n = 0; n < 4; ++n)
            bfr[n] = *(const bf16x8*)&Bs[(wc * 64 + n * 16 + r) * 32 + g * 8];
        #pragma unroll
        for (int m = 0; m < 4; ++m)
            #pragma unroll
            for (int n = 0; n < 4; ++n)
                acc[m][n] = __builtin_amdgcn_mfma_f32_16x16x32_bf16(
                    af[m], bfr[n], acc[m][n], 0, 0, 0);
    }

    float* Cf = (float*)Cout;
    unsigned short* Cb = (unsigned short*)Cout;
    const long long cbase = (long long)z * sC;
    #pragma unroll
    for (int n = 0; n < 4; ++n) {
        int col = n0 + wc * 64 + n * 16 + r;
        float bv = bias ? bias[col] : 0.0f;
        #pragma unroll
        for (int m = 0; m < 4; ++m) {
            int row0 = m0 + wr * 64 + m * 16 + g * 4;
            #pragma unroll
            for (int i = 0; i < 4; ++i) {
                float v = acc[m][n][i] + bv;
                if (RELU) v = fmaxf(v, 0.0f);
                size_t off = (size_t)cbase + (size_t)(row0 + i) * ldc + col;
                if (OUT_BF16) Cb[off] = f2bf(v);
                else          Cf[off] = v;
            }
        }
    }
}

// ---------------------------------------------------------------------------
// scores[b,l,ts] GEMM with fused rel_key B-tiles (conflict-free build).
// A = qh[b] (256x768 bf16), B[n=ts][k=h] = tanh(s_key[s,h]+t_key[t,h]).
// grid (2, 32, 32) = (m-tiles, ts-tiles, batch)
// ---------------------------------------------------------------------------
__global__ __launch_bounds__(256, 2) void scores_kernel(
    const unsigned short* __restrict__ qh,   // [32][256][768]
    const float* __restrict__ s_key,         // [32][64][768]
    const float* __restrict__ t_key,         // [32][64][768]
    unsigned short* __restrict__ scores)     // [32][256][4096]
{
    __shared__ unsigned short As[128 * 32];
    __shared__ unsigned short Bs[128 * 40];  // padded stride 40 shorts
    __shared__ float Sk[64 * 36];            // padded stride 36 floats
    __shared__ float Tk[2 * 32];

    const int b = blockIdx.z;
    const unsigned short* A = qh + (size_t)b * 256 * 768;
    const float* skp = s_key + (size_t)b * 64 * 768;
    const float* tkp = t_key + (size_t)b * 64 * 768;
    const int m0 = blockIdx.x * 128, n0 = blockIdx.y * 128;
    const int t0 = n0 >> 6;                  // two t values per 128-ts tile
    const int tid = threadIdx.x;
    const int lane = tid & 63, wid = tid >> 6;
    const int wr = wid >> 1, wc = wid & 1;
    const int r = lane & 15, g = lane >> 4;

    f32x4 acc[4][4] = {};

    for (int k0 = 0; k0 < 768; k0 += 32) {
        __syncthreads();
        if (tid < 64) Tk[tid] = tkp[(size_t)(t0 + (tid >> 5)) * 768 + k0 + (tid & 31)];
        #pragma unroll
        for (int j = 0; j < 2; ++j) {
            int c = j * 256 + tid;
            int row = c >> 2, kc = (c & 3) * 8;
            async_copy16(&As[c * 8], A + (size_t)(m0 + row) * 768 + k0 + kc);
        }
        // reg-stage s_key chunk into padded Sk: [64 s][32 k], stride 36
        {
            int s = tid >> 2, c4 = (tid & 3) * 8;
            float4 v0 = *(const float4*)&skp[(size_t)s * 768 + k0 + c4];
            float4 v1 = *(const float4*)&skp[(size_t)s * 768 + k0 + c4 + 4];
            *(float4*)&Sk[s * 36 + c4]     = v0;
            *(float4*)&Sk[s * 36 + c4 + 4] = v1;
        }
        asm volatile("s_waitcnt vmcnt(0)" ::: "memory");
        __syncthreads();

        // Bs[n][kk] = bf16(tanh(Sk[n&63][kk] + Tk[n>>6][kk]))
        #pragma unroll
        for (int j = 0; j < 2; ++j) {
            int c = j * 256 + tid;
            int n = c >> 2, kc = (c & 3) * 8;
            const float* sv = &Sk[(n & 63) * 36 + kc];
            const float* tv = &Tk[(n >> 6) * 32 + kc];
            bf16x8 o;
            #pragma unroll
            for (int e = 0; e < 8; ++e)
                o[e] = (short)f2bf(tanh_fast(sv[e] + tv[e]));
            *(bf16x8*)&Bs[n * 40 + kc] = o;
        }
        __syncthreads();

        bf16x8 af[4], bfr[4];
        #pragma unroll
        for (int m = 0; m < 4; ++m)
            af[m] = *(const bf16x8*)&As[(wr * 64 + m * 16 + r) * 32 + g * 8];
        #pragma unroll
        for (int n = 0; n < 4; ++n)
            bfr[n] = *(const bf16x8*)&Bs[(wc * 64 + n * 16 + r) * 40 + g * 8];
        #pragma unroll
        for (int m = 0; m < 4; ++m)
            #pragma unroll
            for (int n = 0; n < 4; ++n)
                acc[m][n] = __builtin_amdgcn_mfma_f32_16x16x32_bf16(
                    af[m], bfr[n], acc[m][n], 0, 0, 0);
    }

    unsigned short* C = scores + (size_t)b * 256 * 4096;
    #pragma unroll
    for (int n = 0; n < 4; ++n) {
        int col = n0 + wc * 64 + n * 16 + r;
        #pragma unroll
        for (int m = 0; m < 4; ++m) {
            int row0 = m0 + wr * 64 + m * 16 + g * 4;
            #pragma unroll
            for (int i = 0; i < 4; ++i)
                C[(size_t)(row0 + i) * 4096 + col] = f2bf(acc[m][n][i]);
        }
    }
}

// ---------------------------------------------------------------------------
// ctx[b,l,h] GEMM, fused rel_key, occupancy-oriented tiling.
// Tile m128 x n64, 4 waves (2m x 2n), acc[4][2]. grid (2, 12, 32) = 768
// blocks -> 3 blocks/CU, 12 waves/CU. s_key/t_key read direct from global
// (per-block slab 16KB, L1-resident). Bs stride 40 (conflict-balanced).
// ---------------------------------------------------------------------------
__global__ __launch_bounds__(256, 3) void ctx_kernel(
    const unsigned short* __restrict__ w,    // [32][256][4096]
    const float* __restrict__ s_key,         // [32][64][768]
    const float* __restrict__ t_key,         // [32][64][768]
    unsigned short* __restrict__ xcat)       // [8192][1536]
{
    __shared__ unsigned short As[128 * 32];
    __shared__ unsigned short Bs[64 * 40];   // [h][ts-local], stride 40 shorts

    const int b = blockIdx.z;
    const unsigned short* A = w + (size_t)b * 256 * 4096;
    const float* skp = s_key + (size_t)b * 64 * 768;
    const float* tkp = t_key + (size_t)b * 64 * 768;
    const int m0 = blockIdx.x * 128, n0 = blockIdx.y * 64;
    const int tid = threadIdx.x;
    const int lane = tid & 63, wid = tid >> 6;
    const int wr = wid >> 1, wc = wid & 1;   // wave: 64m x 32n
    const int r = lane & 15, g = lane >> 4;
    const int sl = tid & 31, hg = tid >> 5;  // build coords: 8 h per thread

    f32x4 acc[4][2] = {};

    for (int k0 = 0; k0 < 4096; k0 += 32) {
        const int t = k0 >> 6, s = (k0 & 63) + sl;   // ts = t*64 + s
        __syncthreads();
        #pragma unroll
        for (int j = 0; j < 2; ++j) {
            int c = j * 256 + tid;
            int row = c >> 2, kc = (c & 3) * 8;
            async_copy16(&As[c * 8], A + (size_t)(m0 + row) * 4096 + k0 + kc);
        }
        // build Bs[h][sl] = tanh(s_key[s][n0+h] + t_key[t][n0+h]), h=hg*8..+7
        {
            const float* sv = &skp[(size_t)s * 768 + n0 + hg * 8];
            const float* tv = &tkp[(size_t)t * 768 + n0 + hg * 8];
            float4 sa = *(const float4*)sv, sb = *(const float4*)(sv + 4);
            float4 ta = *(const float4*)tv, tb = *(const float4*)(tv + 4);
            Bs[(hg * 8 + 0) * 40 + sl] = f2bf(tanh_fast(sa.x + ta.x));
            Bs[(hg * 8 + 1) * 40 + sl] = f2bf(tanh_fast(sa.y + ta.y));
            Bs[(hg * 8 + 2) * 40 + sl] = f2bf(tanh_fast(sa.z + ta.z));
            Bs[(hg * 8 + 3) * 40 + sl] = f2bf(tanh_fast(sa.w + ta.w));
            Bs[(hg * 8 + 4) * 40 + sl] = f2bf(tanh_fast(sb.x + tb.x));
            Bs[(hg * 8 + 5) * 40 + sl] = f2bf(tanh_fast(sb.y + tb.y));
            Bs[(hg * 8 + 6) * 40 + sl] = f2bf(tanh_fast(sb.z + tb.z));
            Bs[(hg * 8 + 7) * 40 + sl] = f2bf(tanh_fast(sb.w + tb.w));
        }
        asm volatile("s_waitcnt vmcnt(0)" ::: "memory");
        __syncthreads();

        bf16x8 af[4], bfr[2];
        #pragma unroll
        for (int m = 0; m < 4; ++m)
            af[m] = *(const bf16x8*)&As[(wr * 64 + m * 16 + r) * 32 + g * 8];
        #pragma unroll
        for (int n = 0; n < 2; ++n)
            bfr[n] = *(const bf16x8*)&Bs[(wc * 32 + n * 16 + r) * 40 + g * 8];
        #pragma unroll
        for (int m = 0; m < 4; ++m)
            #pragma unroll
            for (int n = 0; n < 2; ++n)
                acc[m][n] = __builtin_amdgcn_mfma_f32_16x16x32_bf16(
                    af[m], bfr[n], acc[m][n], 0, 0, 0);
    }

    unsigned short* C = xcat + (size_t)b * 256 * 1536 + 768;
    #pragma unroll
    for (int n = 0; n < 2; ++n) {
        int col = n0 + wc * 32 + n * 16 + r;
        #pragma unroll
        for (int m = 0; m < 4; ++m) {
            int row0 = m0 + wr * 64 + m * 16 + g * 4;
            #pragma unroll
            for (int i = 0; i < 4; ++i)
                C[(size_t)(row0 + i) * 1536 + col] = f2bf(acc[m][n][i]);
        }
    }
}

// ---------------------------------------------------------------------------
// converters / transposes
// ---------------------------------------------------------------------------
__global__ void cvt_bf16_kernel(const float* __restrict__ in,
                                unsigned short* __restrict__ out, int n4) {
    int i = blockIdx.x * 256 + threadIdx.x;
    if (i >= n4) return;
    float4 v = ((const float4*)in)[i];
    ushort4 o;
    o.x = f2bf(v.x); o.y = f2bf(v.y); o.z = f2bf(v.z); o.w = f2bf(v.w);
    ((ushort4*)out)[i] = o;
}

__global__ void cvt_query_kernel(const float* __restrict__ in,
                                 unsigned short* __restrict__ xcat) {
    int i = blockIdx.x * 256 + threadIdx.x;
    if (i >= 8192 * 192) return;
    int row = i / 192, c4 = (i % 192) * 4;
    float4 v = ((const float4*)in)[i];
    ushort4 o;
    o.x = f2bf(v.x); o.y = f2bf(v.y); o.z = f2bf(v.z); o.w = f2bf(v.w);
    *(ushort4*)&xcat[(size_t)row * 1536 + c4] = o;
}

__global__ void transpose_w_kernel(const float* __restrict__ in,
                                   unsigned short* __restrict__ out,
                                   int R, int C) {
    __shared__ float tile[64][65];
    const int r0 = blockIdx.y * 64, c0 = blockIdx.x * 64;
    const int tx = threadIdx.x & 63, ty = threadIdx.x >> 6;
    for (int i = ty; i < 64; i += 4)
        tile[i][tx] = in[(size_t)(r0 + i) * C + c0 + tx];
    __syncthreads();
    for (int i = ty; i < 64; i += 4)
        out[(size_t)(c0 + i) * R + r0 + tx] = f2bf(tile[tx][i]);
}

// ---------------------------------------------------------------------------
// row softmax over 4096 (bf16 in-place), scale 1/sqrt(768) before exp
// ---------------------------------------------------------------------------
__global__ __launch_bounds__(256) void softmax_kernel(unsigned short* __restrict__ scores) {
    unsigned short* p = scores + (size_t)blockIdx.x * 4096;
    const int tid = threadIdx.x, lane = tid & 63, wid = tid >> 6;
    __shared__ float red[4];

    float v[16];
    {
        const bf16x8* p8 = (const bf16x8*)p;
        bf16x8 a = p8[tid * 2], c = p8[tid * 2 + 1];
        #pragma unroll
        for (int e = 0; e < 8; ++e) {
            v[e]     = bf2f((unsigned short)a[e]);
            v[8 + e] = bf2f((unsigned short)c[e]);
        }
    }
    float mx = v[0];
    #pragma unroll
    for (int e = 1; e < 16; ++e) mx = fmaxf(mx, v[e]);
    #pragma unroll
    for (int o = 32; o; o >>= 1) mx = fmaxf(mx, __shfl_xor(mx, o));
    if (lane == 0) red[wid] = mx;
    __syncthreads();
    mx = fmaxf(fmaxf(red[0], red[1]), fmaxf(red[2], red[3]));
    __syncthreads();

    const float scale = 0.03608439182435161f;   // 1/sqrt(768)
    float sum = 0.0f;
    #pragma unroll
    for (int e = 0; e < 16; ++e) {
        v[e] = __expf((v[e] - mx) * scale);
        sum += v[e];
    }
    #pragma unroll
    for (int o = 32; o; o >>= 1) sum += __shfl_xor(sum, o);
    if (lane == 0) red[wid] = sum;
    __syncthreads();
    sum = red[0] + red[1] + red[2] + red[3];
    const float inv = 1.0f / sum;

    bf16x8* p8 = (bf16x8*)p;
    #pragma unroll
    for (int j = 0; j < 2; ++j) {
        bf16x8 o;
        #pragma unroll
        for (int e = 0; e < 8; ++e)
            o[e] = (short)f2bf(v[j * 8 + e] * inv);
        p8[tid * 2 + j] = o;
    }
}

// ---------------------------------------------------------------------------
extern "C" void kernel_launch(void* const* d_in, const int* in_sizes, int n_in,
                              void* d_out, int out_size, void* d_ws, size_t ws_size,
                              hipStream_t stream) {
    const float* query = (const float*)d_in[0];
    const float* src   = (const float*)d_in[1];
    const float* trg   = (const float*)d_in[2];
    const float* Wq    = (const float*)d_in[3];
    const float* b_q   = (const float*)d_in[4];
    const float* Ws    = (const float*)d_in[5];
    const float* b_s   = (const float*)d_in[6];
    const float* Wt    = (const float*)d_in[7];
    const float* b_t   = (const float*)d_in[8];
    const float* Wo    = (const float*)d_in[9];
    const float* b_o   = (const float*)d_in[10];

    char* ws = (char*)d_ws;
    size_t off = 0;
    auto alloc = [&](size_t bytes) {
        void* p = ws + off;
        off += (bytes + 255) & ~(size_t)255;
        return p;
    };
    unsigned short* xcat   = (unsigned short*)alloc((size_t)8192 * 1536 * 2);
    unsigned short* srcbf  = (unsigned short*)alloc((size_t)2048 * 1024 * 2);
    unsigned short* trgbf  = (unsigned short*)alloc((size_t)2048 * 1024 * 2);
    unsigned short* WqT    = (unsigned short*)alloc((size_t)768 * 768 * 2);
    unsigned short* WsT    = (unsigned short*)alloc((size_t)768 * 1024 * 2);
    unsigned short* WtT    = (unsigned short*)alloc((size_t)768 * 1024 * 2);
    unsigned short* WoT    = (unsigned short*)alloc((size_t)768 * 1536 * 2);
    unsigned short* qh     = (unsigned short*)alloc((size_t)8192 * 768 * 2);
    float*          s_key  = (float*)alloc((size_t)2048 * 768 * 4);
    float*          t_key  = (float*)alloc((size_t)2048 * 768 * 4);
    unsigned short* scores = (unsigned short*)alloc((size_t)32 * 256 * 4096 * 2);
    // total ~133 MB (known-safe)

    // 1. input converts
    cvt_query_kernel<<<6144, 256, 0, stream>>>(query, xcat);
    cvt_bf16_kernel<<<2048, 256, 0, stream>>>(src, srcbf, 524288);
    cvt_bf16_kernel<<<2048, 256, 0, stream>>>(trg, trgbf, 524288);

    // 2. weight transposes
    transpose_w_kernel<<<dim3(12, 12), 256, 0, stream>>>(Wq, WqT, 768, 768);
    transpose_w_kernel<<<dim3(12, 16), 256, 0, stream>>>(Ws, WsT, 1024, 768);
    transpose_w_kernel<<<dim3(12, 16), 256, 0, stream>>>(Wt, WtT, 1024, 768);
    transpose_w_kernel<<<dim3(12, 24), 256, 0, stream>>>(Wo, WoT, 1536, 768);

    // 3. projections
    gemm_bt_kernel<true, false><<<dim3(64, 6, 1), 256, 0, stream>>>(
        xcat, WqT, qh, b_q, 8192, 768, 768, 1536, 768, 768, 0, 0, 0);
    gemm_bt_kernel<false, false><<<dim3(16, 6, 1), 256, 0, stream>>>(
        srcbf, WsT, s_key, b_s, 2048, 768, 1024, 1024, 1024, 768, 0, 0, 0);
    gemm_bt_kernel<false, false><<<dim3(16, 6, 1), 256, 0, stream>>>(
        trgbf, WtT, t_key, b_t, 2048, 768, 1024, 1024, 1024, 768, 0, 0, 0);

    // 4. scores (fused rel_key tanh), bf16
    scores_kernel<<<dim3(2, 32, 32), 256, 0, stream>>>(qh, s_key, t_key, scores);

    // 5. softmax in-place
    softmax_kernel<<<8192, 256, 0, stream>>>(scores);

    // 6. ctx (fused rel_key, 768-block tiling) -> xcat[:, 768:]
    ctx_kernel<<<dim3(2, 12, 32), 256, 0, stream>>>(scores, s_key, t_key, xcat);

    // 7. out = relu(xcat @ WoT^T + b_o)
    gemm_bt_kernel<false, true><<<dim3(64, 6, 1), 256, 0, stream>>>(
        xcat, WoT, d_out, b_o, 8192, 768, 1536, 1536, 1536, 768, 0, 0, 0);
}

// Round 7
// 462.352 us; speedup vs baseline: 1.1335x; 1.1335x over previous
//
#include <hip/hip_runtime.h>
#include <math.h>

// ---------------------------------------------------------------------------
// DynamicAttention4 (B=32 L=256 S=T=64 H=768 Q=768 F=1024 OUT=768)
// q=query@Wq+bq; s_key=src@Ws+bs; t_key=trg@Wt+bt
// rel_key[b,t,s,:]=tanh(s_key[b,s,:]+t_key[b,t,:])   (never materialized)
// scores[b,l,ts]=q·rel_key/sqrt(768); softmax over ts=4096
// ctx[b,l,:]=sum_ts w*rel_key; out=relu([query,ctx]@Wo+bo)
//
// Round-7: ctx pipelined. BK=64 (one t per step, 64 steps), double-buffered
// As with 1-step prefetch (latency hidden under build+MFMA), As XOR-swizzled
// (linear dest + inverse-swizzled source + swizzled read). Bs dual-kk
// stride-40 buffers. Mid-iter raw s_barrier (no vmcnt drain); end-of-iter
// __syncthreads provides the needed vmcnt(0) for the prefetch.
// ---------------------------------------------------------------------------

typedef __attribute__((ext_vector_type(8))) short bf16x8;
typedef __attribute__((ext_vector_type(4))) float f32x4;

__device__ __forceinline__ unsigned short f2bf(float f) {
    union { float f; unsigned u; } x; x.f = f;
    unsigned u = x.u;
    return (unsigned short)((u + 0x7fffu + ((u >> 16) & 1u)) >> 16);
}
__device__ __forceinline__ float bf2f(unsigned short h) {
    union { unsigned u; float f; } x; x.u = (unsigned)h << 16;
    return x.f;
}
__device__ __forceinline__ float tanh_fast(float x) {
    float e = __expf(2.0f * x);
    return 1.0f - 2.0f * __builtin_amdgcn_rcpf(1.0f + e);
}
__device__ __forceinline__ void async_copy16(void* lds, const void* g) {
    __builtin_amdgcn_global_load_lds(
        (const __attribute__((address_space(1))) unsigned int*)g,
        (__attribute__((address_space(3))) unsigned int*)lds,
        16, 0, 0);
}

// ---------------------------------------------------------------------------
// Batched bf16 BT-GEMM: C[z][m,n] = sum_k A[z][m,k]*BT[z][n,k] (+bias,+relu)
// 128x128 tile, BK=32, 4 waves, 4x4 16x16x32 frags. Same k-map for A/B.
// ---------------------------------------------------------------------------
template<bool OUT_BF16, bool RELU>
__global__ __launch_bounds__(256, 2) void gemm_bt_kernel(
    const unsigned short* __restrict__ A, const unsigned short* __restrict__ BT,
    void* __restrict__ Cout, const float* __restrict__ bias,
    int M, int N, int K, int lda, int ldb, int ldc,
    long long sA, long long sB, long long sC)
{
    __shared__ unsigned short As[128 * 32];
    __shared__ unsigned short Bs[128 * 32];
    const int z = blockIdx.z;
    A  += (long long)z * sA;
    BT += (long long)z * sB;
    const int m0 = blockIdx.x * 128, n0 = blockIdx.y * 128;
    const int tid = threadIdx.x;
    const int lane = tid & 63, wid = tid >> 6;
    const int wr = wid >> 1, wc = wid & 1;
    const int r = lane & 15, g = lane >> 4;

    f32x4 acc[4][4] = {};

    for (int k0 = 0; k0 < K; k0 += 32) {
        __syncthreads();
        #pragma unroll
        for (int j = 0; j < 2; ++j) {
            int c = j * 256 + tid;
            int row = c >> 2, kc = (c & 3) * 8;
            async_copy16(&As[c * 8], A  + (size_t)(m0 + row) * lda + k0 + kc);
            async_copy16(&Bs[c * 8], BT + (size_t)(n0 + row) * ldb + k0 + kc);
        }
        asm volatile("s_waitcnt vmcnt(0)" ::: "memory");
        __syncthreads();

        bf16x8 af[4], bfr[4];
        #pragma unroll
        for (int m = 0; m < 4; ++m)
            af[m] = *(const bf16x8*)&As[(wr * 64 + m * 16 + r) * 32 + g * 8];
        #pragma unroll
        for (int n = 0; n < 4; ++n)
            bfr[n] = *(const bf16x8*)&Bs[(wc * 64 + n * 16 + r) * 32 + g * 8];
        #pragma unroll
        for (int m = 0; m < 4; ++m)
            #pragma unroll
            for (int n = 0; n < 4; ++n)
                acc[m][n] = __builtin_amdgcn_mfma_f32_16x16x32_bf16(
                    af[m], bfr[n], acc[m][n], 0, 0, 0);
    }

    float* Cf = (float*)Cout;
    unsigned short* Cb = (unsigned short*)Cout;
    const long long cbase = (long long)z * sC;
    #pragma unroll
    for (int n = 0; n < 4; ++n) {
        int col = n0 + wc * 64 + n * 16 + r;
        float bv = bias ? bias[col] : 0.0f;
        #pragma unroll
        for (int m = 0; m < 4; ++m) {
            int row0 = m0 + wr * 64 + m * 16 + g * 4;
            #pragma unroll
            for (int i = 0; i < 4; ++i) {
                float v = acc[m][n][i] + bv;
                if (RELU) v = fmaxf(v, 0.0f);
                size_t off = (size_t)cbase + (size_t)(row0 + i) * ldc + col;
                if (OUT_BF16) Cb[off] = f2bf(v);
                else          Cf[off] = v;
            }
        }
    }
}

// ---------------------------------------------------------------------------
// scores[b,l,ts] GEMM with fused rel_key B-tiles (conflict-free build).
// ---------------------------------------------------------------------------
__global__ __launch_bounds__(256, 2) void scores_kernel(
    const unsigned short* __restrict__ qh,   // [32][256][768]
    const float* __restrict__ s_key,         // [32][64][768]
    const float* __restrict__ t_key,         // [32][64][768]
    unsigned short* __restrict__ scores)     // [32][256][4096]
{
    __shared__ unsigned short As[128 * 32];
    __shared__ unsigned short Bs[128 * 40];  // padded stride 40 shorts
    __shared__ float Sk[64 * 36];            // padded stride 36 floats
    __shared__ float Tk[2 * 32];

    const int b = blockIdx.z;
    const unsigned short* A = qh + (size_t)b * 256 * 768;
    const float* skp = s_key + (size_t)b * 64 * 768;
    const float* tkp = t_key + (size_t)b * 64 * 768;
    const int m0 = blockIdx.x * 128, n0 = blockIdx.y * 128;
    const int t0 = n0 >> 6;                  // two t values per 128-ts tile
    const int tid = threadIdx.x;
    const int lane = tid & 63, wid = tid >> 6;
    const int wr = wid >> 1, wc = wid & 1;
    const int r = lane & 15, g = lane >> 4;

    f32x4 acc[4][4] = {};

    for (int k0 = 0; k0 < 768; k0 += 32) {
        __syncthreads();
        if (tid < 64) Tk[tid] = tkp[(size_t)(t0 + (tid >> 5)) * 768 + k0 + (tid & 31)];
        #pragma unroll
        for (int j = 0; j < 2; ++j) {
            int c = j * 256 + tid;
            int row = c >> 2, kc = (c & 3) * 8;
            async_copy16(&As[c * 8], A + (size_t)(m0 + row) * 768 + k0 + kc);
        }
        // reg-stage s_key chunk into padded Sk: [64 s][32 k], stride 36
        {
            int s = tid >> 2, c4 = (tid & 3) * 8;
            float4 v0 = *(const float4*)&skp[(size_t)s * 768 + k0 + c4];
            float4 v1 = *(const float4*)&skp[(size_t)s * 768 + k0 + c4 + 4];
            *(float4*)&Sk[s * 36 + c4]     = v0;
            *(float4*)&Sk[s * 36 + c4 + 4] = v1;
        }
        asm volatile("s_waitcnt vmcnt(0)" ::: "memory");
        __syncthreads();

        // Bs[n][kk] = bf16(tanh(Sk[n&63][kk] + Tk[n>>6][kk]))
        #pragma unroll
        for (int j = 0; j < 2; ++j) {
            int c = j * 256 + tid;
            int n = c >> 2, kc = (c & 3) * 8;
            const float* sv = &Sk[(n & 63) * 36 + kc];
            const float* tv = &Tk[(n >> 6) * 32 + kc];
            bf16x8 o;
            #pragma unroll
            for (int e = 0; e < 8; ++e)
                o[e] = (short)f2bf(tanh_fast(sv[e] + tv[e]));
            *(bf16x8*)&Bs[n * 40 + kc] = o;
        }
        __syncthreads();

        bf16x8 af[4], bfr[4];
        #pragma unroll
        for (int m = 0; m < 4; ++m)
            af[m] = *(const bf16x8*)&As[(wr * 64 + m * 16 + r) * 32 + g * 8];
        #pragma unroll
        for (int n = 0; n < 4; ++n)
            bfr[n] = *(const bf16x8*)&Bs[(wc * 64 + n * 16 + r) * 40 + g * 8];
        #pragma unroll
        for (int m = 0; m < 4; ++m)
            #pragma unroll
            for (int n = 0; n < 4; ++n)
                acc[m][n] = __builtin_amdgcn_mfma_f32_16x16x32_bf16(
                    af[m], bfr[n], acc[m][n], 0, 0, 0);
    }

    unsigned short* C = scores + (size_t)b * 256 * 4096;
    #pragma unroll
    for (int n = 0; n < 4; ++n) {
        int col = n0 + wc * 64 + n * 16 + r;
        #pragma unroll
        for (int m = 0; m < 4; ++m) {
            int row0 = m0 + wr * 64 + m * 16 + g * 4;
            #pragma unroll
            for (int i = 0; i < 4; ++i)
                C[(size_t)(row0 + i) * 4096 + col] = f2bf(acc[m][n][i]);
        }
    }
}

// ---------------------------------------------------------------------------
// ctx[b,l,h] GEMM, fused rel_key, software-pipelined.
// Tile m128 x n64, BK=64 (one t per step), 64 steps. As double-buffered +
// 1-step prefetch, XOR-swizzled (source pre-swizzle + swizzled read).
// Bs[kk][64h][40] dual buffers. grid (2, 12, 32) = 768 blocks, 3/CU.
// ---------------------------------------------------------------------------
__global__ __launch_bounds__(256, 3) void ctx_kernel(
    const unsigned short* __restrict__ w,    // [32][256][4096]
    const float* __restrict__ s_key,         // [32][64][768]
    const float* __restrict__ t_key,         // [32][64][768]
    unsigned short* __restrict__ xcat)       // [8192][1536]
{
    __shared__ unsigned short As[2][128 * 64];  // 32 KB, swizzled chunks
    __shared__ unsigned short Bs[2][64 * 40];   // 10 KB, [kk][h][s] stride 40

    const int b = blockIdx.z;
    const unsigned short* A = w + (size_t)b * 256 * 4096;
    const float* skp = s_key + (size_t)b * 64 * 768;
    const float* tkp = t_key + (size_t)b * 64 * 768;
    const int m0 = blockIdx.x * 128, n0 = blockIdx.y * 64;
    const int tid = threadIdx.x;
    const int lane = tid & 63, wid = tid >> 6;
    const int wr = wid >> 1, wc = wid & 1;   // wave: 64m x 32n
    const int r = lane & 15, g = lane >> 4;
    const int sl = tid & 31, hg = tid >> 5;  // build coords: 8 h per thread

    // stage t-block into As[d]: 1024 16B chunks, source column pre-swizzled
    auto stage = [&](int d, int t) {
        #pragma unroll
        for (int j = 0; j < 4; ++j) {
            int c = j * 256 + tid;
            int row = c >> 3, pcol = c & 7;
            int gcol = pcol ^ (row & 7);
            async_copy16(&As[d][c * 8],
                         A + (size_t)(m0 + row) * 4096 + t * 64 + gcol * 8);
        }
    };

    f32x4 acc[4][2] = {};

    // prologue: tile t=0 into buf 0
    stage(0, 0);
    asm volatile("s_waitcnt vmcnt(0)" ::: "memory");
    __syncthreads();

    for (int t = 0; t < 64; ++t) {
        const int cur = t & 1;

        // 1. key loads for this t (consumed before prefetch completes)
        const float* tvp = &tkp[(size_t)t * 768 + n0 + hg * 8];
        float4 ta = *(const float4*)tvp, tb = *(const float4*)(tvp + 4);
        const float* sv0 = &skp[(size_t)sl * 768 + n0 + hg * 8];
        const float* sv1 = &skp[(size_t)(32 + sl) * 768 + n0 + hg * 8];
        float4 sa0 = *(const float4*)sv0, sb0 = *(const float4*)(sv0 + 4);
        float4 sa1 = *(const float4*)sv1, sb1 = *(const float4*)(sv1 + 4);

        // 2. issue next-tile prefetch (stays in flight through build+MFMA)
        if (t < 63) stage(cur ^ 1, t + 1);

        // 3. build Bs[kk][h][s] = tanh(s_key + t_key), 16 elems/thread
        {
            int hb = hg * 8;
            Bs[0][(hb + 0) * 40 + sl] = f2bf(tanh_fast(sa0.x + ta.x));
            Bs[0][(hb + 1) * 40 + sl] = f2bf(tanh_fast(sa0.y + ta.y));
            Bs[0][(hb + 2) * 40 + sl] = f2bf(tanh_fast(sa0.z + ta.z));
            Bs[0][(hb + 3) * 40 + sl] = f2bf(tanh_fast(sa0.w + ta.w));
            Bs[0][(hb + 4) * 40 + sl] = f2bf(tanh_fast(sb0.x + tb.x));
            Bs[0][(hb + 5) * 40 + sl] = f2bf(tanh_fast(sb0.y + tb.y));
            Bs[0][(hb + 6) * 40 + sl] = f2bf(tanh_fast(sb0.z + tb.z));
            Bs[0][(hb + 7) * 40 + sl] = f2bf(tanh_fast(sb0.w + tb.w));
            Bs[1][(hb + 0) * 40 + sl] = f2bf(tanh_fast(sa1.x + ta.x));
            Bs[1][(hb + 1) * 40 + sl] = f2bf(tanh_fast(sa1.y + ta.y));
            Bs[1][(hb + 2) * 40 + sl] = f2bf(tanh_fast(sa1.z + ta.z));
            Bs[1][(hb + 3) * 40 + sl] = f2bf(tanh_fast(sa1.w + ta.w));
            Bs[1][(hb + 4) * 40 + sl] = f2bf(tanh_fast(sb1.x + tb.x));
            Bs[1][(hb + 5) * 40 + sl] = f2bf(tanh_fast(sb1.y + tb.y));
            Bs[1][(hb + 6) * 40 + sl] = f2bf(tanh_fast(sb1.z + tb.z));
            Bs[1][(hb + 7) * 40 + sl] = f2bf(tanh_fast(sb1.w + tb.w));
        }

        // 4. Bs-ready barrier WITHOUT vmcnt drain (prefetch stays in flight)
        asm volatile("s_waitcnt lgkmcnt(0)" ::: "memory");
        __builtin_amdgcn_sched_barrier(0);
        __builtin_amdgcn_s_barrier();
        __builtin_amdgcn_sched_barrier(0);

        // 5. MFMA over kk halves (As read swizzled)
        #pragma unroll
        for (int kk = 0; kk < 2; ++kk) {
            bf16x8 af[4], bfr[2];
            #pragma unroll
            for (int m = 0; m < 4; ++m) {
                int rowr = wr * 64 + m * 16 + r;
                int phys = (kk * 4 + g) ^ (rowr & 7);
                af[m] = *(const bf16x8*)&As[cur][rowr * 64 + phys * 8];
            }
            #pragma unroll
            for (int n = 0; n < 2; ++n)
                bfr[n] = *(const bf16x8*)&Bs[kk][(wc * 32 + n * 16 + r) * 40 + g * 8];
            #pragma unroll
            for (int m = 0; m < 4; ++m)
                #pragma unroll
                for (int n = 0; n < 2; ++n)
                    acc[m][n] = __builtin_amdgcn_mfma_f32_16x16x32_bf16(
                        af[m], bfr[n], acc[m][n], 0, 0, 0);
        }

        // 6. end-of-iter: implicit vmcnt(0)+lgkmcnt(0) drain = As[next] landed,
        //    all readers done -> safe to rebuild Bs / overwrite As[cur] next iter
        __syncthreads();
    }

    unsigned short* C = xcat + (size_t)b * 256 * 1536 + 768;
    #pragma unroll
    for (int n = 0; n < 2; ++n) {
        int col = n0 + wc * 32 + n * 16 + r;
        #pragma unroll
        for (int m = 0; m < 4; ++m) {
            int row0 = m0 + wr * 64 + m * 16 + g * 4;
            #pragma unroll
            for (int i = 0; i < 4; ++i)
                C[(size_t)(row0 + i) * 1536 + col] = f2bf(acc[m][n][i]);
        }
    }
}

// ---------------------------------------------------------------------------
// converters / transposes
// ---------------------------------------------------------------------------
__global__ void cvt_bf16_kernel(const float* __restrict__ in,
                                unsigned short* __restrict__ out, int n4) {
    int i = blockIdx.x * 256 + threadIdx.x;
    if (i >= n4) return;
    float4 v = ((const float4*)in)[i];
    ushort4 o;
    o.x = f2bf(v.x); o.y = f2bf(v.y); o.z = f2bf(v.z); o.w = f2bf(v.w);
    ((ushort4*)out)[i] = o;
}

__global__ void cvt_query_kernel(const float* __restrict__ in,
                                 unsigned short* __restrict__ xcat) {
    int i = blockIdx.x * 256 + threadIdx.x;
    if (i >= 8192 * 192) return;
    int row = i / 192, c4 = (i % 192) * 4;
    float4 v = ((const float4*)in)[i];
    ushort4 o;
    o.x = f2bf(v.x); o.y = f2bf(v.y); o.z = f2bf(v.z); o.w = f2bf(v.w);
    *(ushort4*)&xcat[(size_t)row * 1536 + c4] = o;
}

__global__ void transpose_w_kernel(const float* __restrict__ in,
                                   unsigned short* __restrict__ out,
                                   int R, int C) {
    __shared__ float tile[64][65];
    const int r0 = blockIdx.y * 64, c0 = blockIdx.x * 64;
    const int tx = threadIdx.x & 63, ty = threadIdx.x >> 6;
    for (int i = ty; i < 64; i += 4)
        tile[i][tx] = in[(size_t)(r0 + i) * C + c0 + tx];
    __syncthreads();
    for (int i = ty; i < 64; i += 4)
        out[(size_t)(c0 + i) * R + r0 + tx] = f2bf(tile[tx][i]);
}

// ---------------------------------------------------------------------------
// row softmax over 4096 (bf16 in-place), scale 1/sqrt(768) before exp
// ---------------------------------------------------------------------------
__global__ __launch_bounds__(256) void softmax_kernel(unsigned short* __restrict__ scores) {
    unsigned short* p = scores + (size_t)blockIdx.x * 4096;
    const int tid = threadIdx.x, lane = tid & 63, wid = tid >> 6;
    __shared__ float red[4];

    float v[16];
    {
        const bf16x8* p8 = (const bf16x8*)p;
        bf16x8 a = p8[tid * 2], c = p8[tid * 2 + 1];
        #pragma unroll
        for (int e = 0; e < 8; ++e) {
            v[e]     = bf2f((unsigned short)a[e]);
            v[8 + e] = bf2f((unsigned short)c[e]);
        }
    }
    float mx = v[0];
    #pragma unroll
    for (int e = 1; e < 16; ++e) mx = fmaxf(mx, v[e]);
    #pragma unroll
    for (int o = 32; o; o >>= 1) mx = fmaxf(mx, __shfl_xor(mx, o));
    if (lane == 0) red[wid] = mx;
    __syncthreads();
    mx = fmaxf(fmaxf(red[0], red[1]), fmaxf(red[2], red[3]));
    __syncthreads();

    const float scale = 0.03608439182435161f;   // 1/sqrt(768)
    float sum = 0.0f;
    #pragma unroll
    for (int e = 0; e < 16; ++e) {
        v[e] = __expf((v[e] - mx) * scale);
        sum += v[e];
    }
    #pragma unroll
    for (int o = 32; o; o >>= 1) sum += __shfl_xor(sum, o);
    if (lane == 0) red[wid] = sum;
    __syncthreads();
    sum = red[0] + red[1] + red[2] + red[3];
    const float inv = 1.0f / sum;

    bf16x8* p8 = (bf16x8*)p;
    #pragma unroll
    for (int j = 0; j < 2; ++j) {
        bf16x8 o;
        #pragma unroll
        for (int e = 0; e < 8; ++e)
            o[e] = (short)f2bf(v[j * 8 + e] * inv);
        p8[tid * 2 + j] = o;
    }
}

// ---------------------------------------------------------------------------
extern "C" void kernel_launch(void* const* d_in, const int* in_sizes, int n_in,
                              void* d_out, int out_size, void* d_ws, size_t ws_size,
                              hipStream_t stream) {
    const float* query = (const float*)d_in[0];
    const float* src   = (const float*)d_in[1];
    const float* trg   = (const float*)d_in[2];
    const float* Wq    = (const float*)d_in[3];
    const float* b_q   = (const float*)d_in[4];
    const float* Ws    = (const float*)d_in[5];
    const float* b_s   = (const float*)d_in[6];
    const float* Wt    = (const float*)d_in[7];
    const float* b_t   = (const float*)d_in[8];
    const float* Wo    = (const float*)d_in[9];
    const float* b_o   = (const float*)d_in[10];

    char* ws = (char*)d_ws;
    size_t off = 0;
    auto alloc = [&](size_t bytes) {
        void* p = ws + off;
        off += (bytes + 255) & ~(size_t)255;
        return p;
    };
    unsigned short* xcat   = (unsigned short*)alloc((size_t)8192 * 1536 * 2);
    unsigned short* srcbf  = (unsigned short*)alloc((size_t)2048 * 1024 * 2);
    unsigned short* trgbf  = (unsigned short*)alloc((size_t)2048 * 1024 * 2);
    unsigned short* WqT    = (unsigned short*)alloc((size_t)768 * 768 * 2);
    unsigned short* WsT    = (unsigned short*)alloc((size_t)768 * 1024 * 2);
    unsigned short* WtT    = (unsigned short*)alloc((size_t)768 * 1024 * 2);
    unsigned short* WoT    = (unsigned short*)alloc((size_t)768 * 1536 * 2);
    unsigned short* qh     = (unsigned short*)alloc((size_t)8192 * 768 * 2);
    float*          s_key  = (float*)alloc((size_t)2048 * 768 * 4);
    float*          t_key  = (float*)alloc((size_t)2048 * 768 * 4);
    unsigned short* scores = (unsigned short*)alloc((size_t)32 * 256 * 4096 * 2);
    // total ~133 MB (known-safe)

    // 1. input converts
    cvt_query_kernel<<<6144, 256, 0, stream>>>(query, xcat);
    cvt_bf16_kernel<<<2048, 256, 0, stream>>>(src, srcbf, 524288);
    cvt_bf16_kernel<<<2048, 256, 0, stream>>>(trg, trgbf, 524288);

    // 2. weight transposes
    transpose_w_kernel<<<dim3(12, 12), 256, 0, stream>>>(Wq, WqT, 768, 768);
    transpose_w_kernel<<<dim3(12, 16), 256, 0, stream>>>(Ws, WsT, 1024, 768);
    transpose_w_kernel<<<dim3(12, 16), 256, 0, stream>>>(Wt, WtT, 1024, 768);
    transpose_w_kernel<<<dim3(12, 24), 256, 0, stream>>>(Wo, WoT, 1536, 768);

    // 3. projections
    gemm_bt_kernel<true, false><<<dim3(64, 6, 1), 256, 0, stream>>>(
        xcat, WqT, qh, b_q, 8192, 768, 768, 1536, 768, 768, 0, 0, 0);
    gemm_bt_kernel<false, false><<<dim3(16, 6, 1), 256, 0, stream>>>(
        srcbf, WsT, s_key, b_s, 2048, 768, 1024, 1024, 1024, 768, 0, 0, 0);
    gemm_bt_kernel<false, false><<<dim3(16, 6, 1), 256, 0, stream>>>(
        trgbf, WtT, t_key, b_t, 2048, 768, 1024, 1024, 1024, 768, 0, 0, 0);

    // 4. scores (fused rel_key tanh), bf16
    scores_kernel<<<dim3(2, 32, 32), 256, 0, stream>>>(qh, s_key, t_key, scores);

    // 5. softmax in-place
    softmax_kernel<<<8192, 256, 0, stream>>>(scores);

    // 6. ctx (fused rel_key, pipelined BK=64) -> xcat[:, 768:]
    ctx_kernel<<<dim3(2, 12, 32), 256, 0, stream>>>(scores, s_key, t_key, xcat);

    // 7. out = relu(xcat @ WoT^T + b_o)
    gemm_bt_kernel<false, true><<<dim3(64, 6, 1), 256, 0, stream>>>(
        xcat, WoT, d_out, b_o, 8192, 768, 1536, 1536, 1536, 768, 0, 0, 0);
}

// Round 9
// 453.597 us; speedup vs baseline: 1.1554x; 1.0193x over previous
//
#include <hip/hip_runtime.h>
#include <math.h>

// ---------------------------------------------------------------------------
// DynamicAttention4 (B=32 L=256 S=T=64 H=768 Q=768 F=1024 OUT=768)
// q=query@Wq+bq; s_key=src@Ws+bs; t_key=trg@Wt+bt
// rel_key[b,t,s,:]=tanh(s_key[b,s,:]+t_key[b,t,:])   (never materialized)
// scores[b,l,ts]=q·rel_key/sqrt(768); softmax over ts=4096
// ctx[b,l,:]=sum_ts w*rel_key; out=relu([query,ctx]@Wo+bo)
//
// Round-9 == round-8 resubmit (GPU acquisition timed out; no data).
// Full-M (m256) tiles for both fused attention GEMMs -> tanh redundancy
// eliminated, MFMA:VALU doubled; round-7 pipeline (dbuf As + prefetch +
// raw mid-iter barrier) in both.
// ---------------------------------------------------------------------------

typedef __attribute__((ext_vector_type(8))) short bf16x8;
typedef __attribute__((ext_vector_type(4))) float f32x4;

__device__ __forceinline__ unsigned short f2bf(float f) {
    union { float f; unsigned u; } x; x.f = f;
    unsigned u = x.u;
    return (unsigned short)((u + 0x7fffu + ((u >> 16) & 1u)) >> 16);
}
__device__ __forceinline__ float bf2f(unsigned short h) {
    union { unsigned u; float f; } x; x.u = (unsigned)h << 16;
    return x.f;
}
__device__ __forceinline__ float tanh_fast(float x) {
    float e = __expf(2.0f * x);
    return 1.0f - 2.0f * __builtin_amdgcn_rcpf(1.0f + e);
}
__device__ __forceinline__ void async_copy16(void* lds, const void* g) {
    __builtin_amdgcn_global_load_lds(
        (const __attribute__((address_space(1))) unsigned int*)g,
        (__attribute__((address_space(3))) unsigned int*)lds,
        16, 0, 0);
}

// ---------------------------------------------------------------------------
// Batched bf16 BT-GEMM: C[z][m,n] = sum_k A[z][m,k]*BT[z][n,k] (+bias,+relu)
// 128x128 tile, BK=32, 4 waves, 4x4 16x16x32 frags. Same k-map for A/B.
// ---------------------------------------------------------------------------
template<bool OUT_BF16, bool RELU>
__global__ __launch_bounds__(256, 2) void gemm_bt_kernel(
    const unsigned short* __restrict__ A, const unsigned short* __restrict__ BT,
    void* __restrict__ Cout, const float* __restrict__ bias,
    int M, int N, int K, int lda, int ldb, int ldc,
    long long sA, long long sB, long long sC)
{
    __shared__ unsigned short As[128 * 32];
    __shared__ unsigned short Bs[128 * 32];
    const int z = blockIdx.z;
    A  += (long long)z * sA;
    BT += (long long)z * sB;
    const int m0 = blockIdx.x * 128, n0 = blockIdx.y * 128;
    const int tid = threadIdx.x;
    const int lane = tid & 63, wid = tid >> 6;
    const int wr = wid >> 1, wc = wid & 1;
    const int r = lane & 15, g = lane >> 4;

    f32x4 acc[4][4] = {};

    for (int k0 = 0; k0 < K; k0 += 32) {
        __syncthreads();
        #pragma unroll
        for (int j = 0; j < 2; ++j) {
            int c = j * 256 + tid;
            int row = c >> 2, kc = (c & 3) * 8;
            async_copy16(&As[c * 8], A  + (size_t)(m0 + row) * lda + k0 + kc);
            async_copy16(&Bs[c * 8], BT + (size_t)(n0 + row) * ldb + k0 + kc);
        }
        asm volatile("s_waitcnt vmcnt(0)" ::: "memory");
        __syncthreads();

        bf16x8 af[4], bfr[4];
        #pragma unroll
        for (int m = 0; m < 4; ++m)
            af[m] = *(const bf16x8*)&As[(wr * 64 + m * 16 + r) * 32 + g * 8];
        #pragma unroll
        for (int n = 0; n < 4; ++n)
            bfr[n] = *(const bf16x8*)&Bs[(wc * 64 + n * 16 + r) * 32 + g * 8];
        #pragma unroll
        for (int m = 0; m < 4; ++m)
            #pragma unroll
            for (int n = 0; n < 4; ++n)
                acc[m][n] = __builtin_amdgcn_mfma_f32_16x16x32_bf16(
                    af[m], bfr[n], acc[m][n], 0, 0, 0);
    }

    float* Cf = (float*)Cout;
    unsigned short* Cb = (unsigned short*)Cout;
    const long long cbase = (long long)z * sC;
    #pragma unroll
    for (int n = 0; n < 4; ++n) {
        int col = n0 + wc * 64 + n * 16 + r;
        float bv = bias ? bias[col] : 0.0f;
        #pragma unroll
        for (int m = 0; m < 4; ++m) {
            int row0 = m0 + wr * 64 + m * 16 + g * 4;
            #pragma unroll
            for (int i = 0; i < 4; ++i) {
                float v = acc[m][n][i] + bv;
                if (RELU) v = fmaxf(v, 0.0f);
                size_t off = (size_t)cbase + (size_t)(row0 + i) * ldc + col;
                if (OUT_BF16) Cb[off] = f2bf(v);
                else          Cf[off] = v;
            }
        }
    }
}

// ---------------------------------------------------------------------------
// scores[b,l,ts] fused GEMM, m256 x n64 (one t per block), 512 threads,
// 8 waves (4m x 2n), acc[4][2]. As(qh) double-buffered + prefetched.
// Keys read direct from global (L1-resident slab). grid (1, 64, 32).
// ---------------------------------------------------------------------------
__global__ __launch_bounds__(512, 4) void scores_kernel(
    const unsigned short* __restrict__ qh,   // [32][256][768]
    const float* __restrict__ s_key,         // [32][64][768]
    const float* __restrict__ t_key,         // [32][64][768]
    unsigned short* __restrict__ scores)     // [32][256][4096]
{
    __shared__ unsigned short As[2][256 * 32];   // 2 x 16 KB
    __shared__ unsigned short Bs[64 * 40];       // [s][k] stride 40

    const int b = blockIdx.z;
    const int t = blockIdx.y;                    // ts window = t*64 .. +63
    const unsigned short* A = qh + (size_t)b * 256 * 768;
    const float* skp = s_key + (size_t)b * 64 * 768;
    const float* tkr = t_key + ((size_t)b * 64 + t) * 768;
    const int tid = threadIdx.x;
    const int lane = tid & 63, wid = tid >> 6;
    const int wr = wid >> 1, wc = wid & 1;       // 4m x 2n waves
    const int r = lane & 15, g = lane >> 4;
    const int sn = tid >> 3;                     // Bs row (s), 0..63
    const int kc4 = (tid & 7) * 4;               // 4 k-floats per thread

    auto stage = [&](int d, int k0) {
        #pragma unroll
        for (int j = 0; j < 2; ++j) {
            int c = j * 512 + tid;               // 1024 chunks (256 rows x 4)
            int row = c >> 2, kc = (c & 3) * 8;
            async_copy16(&As[d][c * 8], A + (size_t)row * 768 + k0 + kc);
        }
    };

    f32x4 acc[4][2] = {};

    stage(0, 0);
    asm volatile("s_waitcnt vmcnt(0)" ::: "memory");
    __syncthreads();

    for (int ks = 0; ks < 24; ++ks) {
        const int k0 = ks * 32, cur = ks & 1;

        // key loads for this k-window (issued before prefetch)
        float4 sv = *(const float4*)&skp[(size_t)sn * 768 + k0 + kc4];
        float4 tv = *(const float4*)&tkr[k0 + kc4];

        if (ks < 23) stage(cur ^ 1, k0 + 32);

        Bs[sn * 40 + kc4 + 0] = f2bf(tanh_fast(sv.x + tv.x));
        Bs[sn * 40 + kc4 + 1] = f2bf(tanh_fast(sv.y + tv.y));
        Bs[sn * 40 + kc4 + 2] = f2bf(tanh_fast(sv.z + tv.z));
        Bs[sn * 40 + kc4 + 3] = f2bf(tanh_fast(sv.w + tv.w));

        asm volatile("s_waitcnt lgkmcnt(0)" ::: "memory");
        __builtin_amdgcn_sched_barrier(0);
        __builtin_amdgcn_s_barrier();
        __builtin_amdgcn_sched_barrier(0);

        bf16x8 af[4], bfr[2];
        #pragma unroll
        for (int m = 0; m < 4; ++m)
            af[m] = *(const bf16x8*)&As[cur][(wr * 64 + m * 16 + r) * 32 + g * 8];
        #pragma unroll
        for (int n = 0; n < 2; ++n)
            bfr[n] = *(const bf16x8*)&Bs[(wc * 32 + n * 16 + r) * 40 + g * 8];
        #pragma unroll
        for (int m = 0; m < 4; ++m)
            #pragma unroll
            for (int n = 0; n < 2; ++n)
                acc[m][n] = __builtin_amdgcn_mfma_f32_16x16x32_bf16(
                    af[m], bfr[n], acc[m][n], 0, 0, 0);

        __syncthreads();   // drains prefetch; protects Bs/As reuse
    }

    unsigned short* C = scores + (size_t)b * 256 * 4096 + t * 64;
    #pragma unroll
    for (int n = 0; n < 2; ++n) {
        int col = wc * 32 + n * 16 + r;
        #pragma unroll
        for (int m = 0; m < 4; ++m) {
            int row0 = wr * 64 + m * 16 + g * 4;
            #pragma unroll
            for (int i = 0; i < 4; ++i)
                C[(size_t)(row0 + i) * 4096 + col] = f2bf(acc[m][n][i]);
        }
    }
}

// ---------------------------------------------------------------------------
// ctx[b,l,h] fused GEMM, m256 x n64, 512 threads, 8 waves (4m x 2n),
// acc[4][2]. BK=64 (one t per step, 64 steps). As double-buffered +
// prefetched + XOR-swizzled. Bs dual-kk stride-40. grid (1, 12, 32).
// ---------------------------------------------------------------------------
__global__ __launch_bounds__(512, 4) void ctx_kernel(
    const unsigned short* __restrict__ w,    // [32][256][4096]
    const float* __restrict__ s_key,         // [32][64][768]
    const float* __restrict__ t_key,         // [32][64][768]
    unsigned short* __restrict__ xcat)       // [8192][1536]
{
    __shared__ unsigned short As[2][256 * 64];   // 2 x 32 KB, swizzled
    __shared__ unsigned short Bs[2][64 * 40];    // [kk][h][s] stride 40

    const int b = blockIdx.z;
    const unsigned short* A = w + (size_t)b * 256 * 4096;
    const float* skp = s_key + (size_t)b * 64 * 768;
    const float* tkp = t_key + (size_t)b * 64 * 768;
    const int n0 = blockIdx.y * 64;
    const int tid = threadIdx.x;
    const int lane = tid & 63, wid = tid >> 6;
    const int wr = wid >> 1, wc = wid & 1;       // 4m x 2n waves
    const int r = lane & 15, g = lane >> 4;
    const int kkb = tid >> 8;                    // build: kk half (0/1)
    const int sl = tid & 31;                     // build: s within half
    const int hg = (tid >> 5) & 7;               // build: 8 h per thread

    auto stage = [&](int d, int t) {
        #pragma unroll
        for (int j = 0; j < 4; ++j) {
            int c = j * 512 + tid;               // 2048 chunks (256 rows x 8)
            int row = c >> 3, pcol = c & 7;
            int gcol = pcol ^ (row & 7);
            async_copy16(&As[d][c * 8],
                         A + (size_t)row * 4096 + t * 64 + gcol * 8);
        }
    };

    f32x4 acc[4][2] = {};

    stage(0, 0);
    asm volatile("s_waitcnt vmcnt(0)" ::: "memory");
    __syncthreads();

    for (int t = 0; t < 64; ++t) {
        const int cur = t & 1;

        // key loads for this t (consumed before prefetch completes)
        const float* tvp = &tkp[(size_t)t * 768 + n0 + hg * 8];
        const float* svp = &skp[(size_t)(kkb * 32 + sl) * 768 + n0 + hg * 8];
        float4 ta = *(const float4*)tvp, tb = *(const float4*)(tvp + 4);
        float4 sa = *(const float4*)svp, sb = *(const float4*)(svp + 4);

        if (t < 63) stage(cur ^ 1, t + 1);

        // build Bs[kkb][h][sl] = tanh(s_key + t_key), 8 h per thread
        {
            int hb = hg * 8;
            Bs[kkb][(hb + 0) * 40 + sl] = f2bf(tanh_fast(sa.x + ta.x));
            Bs[kkb][(hb + 1) * 40 + sl] = f2bf(tanh_fast(sa.y + ta.y));
            Bs[kkb][(hb + 2) * 40 + sl] = f2bf(tanh_fast(sa.z + ta.z));
            Bs[kkb][(hb + 3) * 40 + sl] = f2bf(tanh_fast(sa.w + ta.w));
            Bs[kkb][(hb + 4) * 40 + sl] = f2bf(tanh_fast(sb.x + tb.x));
            Bs[kkb][(hb + 5) * 40 + sl] = f2bf(tanh_fast(sb.y + tb.y));
            Bs[kkb][(hb + 6) * 40 + sl] = f2bf(tanh_fast(sb.z + tb.z));
            Bs[kkb][(hb + 7) * 40 + sl] = f2bf(tanh_fast(sb.w + tb.w));
        }

        // Bs-ready barrier WITHOUT vmcnt drain (prefetch stays in flight)
        asm volatile("s_waitcnt lgkmcnt(0)" ::: "memory");
        __builtin_amdgcn_sched_barrier(0);
        __builtin_amdgcn_s_barrier();
        __builtin_amdgcn_sched_barrier(0);

        #pragma unroll
        for (int kk = 0; kk < 2; ++kk) {
            bf16x8 af[4], bfr[2];
            #pragma unroll
            for (int m = 0; m < 4; ++m) {
                int rowr = wr * 64 + m * 16 + r;
                int phys = (kk * 4 + g) ^ (rowr & 7);
                af[m] = *(const bf16x8*)&As[cur][rowr * 64 + phys * 8];
            }
            #pragma unroll
            for (int n = 0; n < 2; ++n)
                bfr[n] = *(const bf16x8*)&Bs[kk][(wc * 32 + n * 16 + r) * 40 + g * 8];
            #pragma unroll
            for (int m = 0; m < 4; ++m)
                #pragma unroll
                for (int n = 0; n < 2; ++n)
                    acc[m][n] = __builtin_amdgcn_mfma_f32_16x16x32_bf16(
                        af[m], bfr[n], acc[m][n], 0, 0, 0);
        }

        __syncthreads();   // drains prefetch; protects As/Bs reuse
    }

    unsigned short* C = xcat + (size_t)b * 256 * 1536 + 768;
    #pragma unroll
    for (int n = 0; n < 2; ++n) {
        int col = n0 + wc * 32 + n * 16 + r;
        #pragma unroll
        for (int m = 0; m < 4; ++m) {
            int row0 = wr * 64 + m * 16 + g * 4;
            #pragma unroll
            for (int i = 0; i < 4; ++i)
                C[(size_t)(row0 + i) * 1536 + col] = f2bf(acc[m][n][i]);
        }
    }
}

// ---------------------------------------------------------------------------
// converters / transposes
// ---------------------------------------------------------------------------
__global__ void cvt_bf16_kernel(const float* __restrict__ in,
                                unsigned short* __restrict__ out, int n4) {
    int i = blockIdx.x * 256 + threadIdx.x;
    if (i >= n4) return;
    float4 v = ((const float4*)in)[i];
    ushort4 o;
    o.x = f2bf(v.x); o.y = f2bf(v.y); o.z = f2bf(v.z); o.w = f2bf(v.w);
    ((ushort4*)out)[i] = o;
}

__global__ void cvt_query_kernel(const float* __restrict__ in,
                                 unsigned short* __restrict__ xcat) {
    int i = blockIdx.x * 256 + threadIdx.x;
    if (i >= 8192 * 192) return;
    int row = i / 192, c4 = (i % 192) * 4;
    float4 v = ((const float4*)in)[i];
    ushort4 o;
    o.x = f2bf(v.x); o.y = f2bf(v.y); o.z = f2bf(v.z); o.w = f2bf(v.w);
    *(ushort4*)&xcat[(size_t)row * 1536 + c4] = o;
}

__global__ void transpose_w_kernel(const float* __restrict__ in,
                                   unsigned short* __restrict__ out,
                                   int R, int C) {
    __shared__ float tile[64][65];
    const int r0 = blockIdx.y * 64, c0 = blockIdx.x * 64;
    const int tx = threadIdx.x & 63, ty = threadIdx.x >> 6;
    for (int i = ty; i < 64; i += 4)
        tile[i][tx] = in[(size_t)(r0 + i) * C + c0 + tx];
    __syncthreads();
    for (int i = ty; i < 64; i += 4)
        out[(size_t)(c0 + i) * R + r0 + tx] = f2bf(tile[tx][i]);
}

// ---------------------------------------------------------------------------
// row softmax over 4096 (bf16 in-place), scale 1/sqrt(768) before exp
// ---------------------------------------------------------------------------
__global__ __launch_bounds__(256) void softmax_kernel(unsigned short* __restrict__ scores) {
    unsigned short* p = scores + (size_t)blockIdx.x * 4096;
    const int tid = threadIdx.x, lane = tid & 63, wid = tid >> 6;
    __shared__ float red[4];

    float v[16];
    {
        const bf16x8* p8 = (const bf16x8*)p;
        bf16x8 a = p8[tid * 2], c = p8[tid * 2 + 1];
        #pragma unroll
        for (int e = 0; e < 8; ++e) {
            v[e]     = bf2f((unsigned short)a[e]);
            v[8 + e] = bf2f((unsigned short)c[e]);
        }
    }
    float mx = v[0];
    #pragma unroll
    for (int e = 1; e < 16; ++e) mx = fmaxf(mx, v[e]);
    #pragma unroll
    for (int o = 32; o; o >>= 1) mx = fmaxf(mx, __shfl_xor(mx, o));
    if (lane == 0) red[wid] = mx;
    __syncthreads();
    mx = fmaxf(fmaxf(red[0], red[1]), fmaxf(red[2], red[3]));
    __syncthreads();

    const float scale = 0.03608439182435161f;   // 1/sqrt(768)
    float sum = 0.0f;
    #pragma unroll
    for (int e = 0; e < 16; ++e) {
        v[e] = __expf((v[e] - mx) * scale);
        sum += v[e];
    }
    #pragma unroll
    for (int o = 32; o; o >>= 1) sum += __shfl_xor(sum, o);
    if (lane == 0) red[wid] = sum;
    __syncthreads();
    sum = red[0] + red[1] + red[2] + red[3];
    const float inv = 1.0f / sum;

    bf16x8* p8 = (bf16x8*)p;
    #pragma unroll
    for (int j = 0; j < 2; ++j) {
        bf16x8 o;
        #pragma unroll
        for (int e = 0; e < 8; ++e)
            o[e] = (short)f2bf(v[j * 8 + e] * inv);
        p8[tid * 2 + j] = o;
    }
}

// ---------------------------------------------------------------------------
extern "C" void kernel_launch(void* const* d_in, const int* in_sizes, int n_in,
                              void* d_out, int out_size, void* d_ws, size_t ws_size,
                              hipStream_t stream) {
    const float* query = (const float*)d_in[0];
    const float* src   = (const float*)d_in[1];
    const float* trg   = (const float*)d_in[2];
    const float* Wq    = (const float*)d_in[3];
    const float* b_q   = (const float*)d_in[4];
    const float* Ws    = (const float*)d_in[5];
    const float* b_s   = (const float*)d_in[6];
    const float* Wt    = (const float*)d_in[7];
    const float* b_t   = (const float*)d_in[8];
    const float* Wo    = (const float*)d_in[9];
    const float* b_o   = (const float*)d_in[10];

    char* ws = (char*)d_ws;
    size_t off = 0;
    auto alloc = [&](size_t bytes) {
        void* p = ws + off;
        off += (bytes + 255) & ~(size_t)255;
        return p;
    };
    unsigned short* xcat   = (unsigned short*)alloc((size_t)8192 * 1536 * 2);
    unsigned short* srcbf  = (unsigned short*)alloc((size_t)2048 * 1024 * 2);
    unsigned short* trgbf  = (unsigned short*)alloc((size_t)2048 * 1024 * 2);
    unsigned short* WqT    = (unsigned short*)alloc((size_t)768 * 768 * 2);
    unsigned short* WsT    = (unsigned short*)alloc((size_t)768 * 1024 * 2);
    unsigned short* WtT    = (unsigned short*)alloc((size_t)768 * 1024 * 2);
    unsigned short* WoT    = (unsigned short*)alloc((size_t)768 * 1536 * 2);
    unsigned short* qh     = (unsigned short*)alloc((size_t)8192 * 768 * 2);
    float*          s_key  = (float*)alloc((size_t)2048 * 768 * 4);
    float*          t_key  = (float*)alloc((size_t)2048 * 768 * 4);
    unsigned short* scores = (unsigned short*)alloc((size_t)32 * 256 * 4096 * 2);
    // total ~133 MB (known-safe)

    // 1. input converts
    cvt_query_kernel<<<6144, 256, 0, stream>>>(query, xcat);
    cvt_bf16_kernel<<<2048, 256, 0, stream>>>(src, srcbf, 524288);
    cvt_bf16_kernel<<<2048, 256, 0, stream>>>(trg, trgbf, 524288);

    // 2. weight transposes
    transpose_w_kernel<<<dim3(12, 12), 256, 0, stream>>>(Wq, WqT, 768, 768);
    transpose_w_kernel<<<dim3(12, 16), 256, 0, stream>>>(Ws, WsT, 1024, 768);
    transpose_w_kernel<<<dim3(12, 16), 256, 0, stream>>>(Wt, WtT, 1024, 768);
    transpose_w_kernel<<<dim3(12, 24), 256, 0, stream>>>(Wo, WoT, 1536, 768);

    // 3. projections
    gemm_bt_kernel<true, false><<<dim3(64, 6, 1), 256, 0, stream>>>(
        xcat, WqT, qh, b_q, 8192, 768, 768, 1536, 768, 768, 0, 0, 0);
    gemm_bt_kernel<false, false><<<dim3(16, 6, 1), 256, 0, stream>>>(
        srcbf, WsT, s_key, b_s, 2048, 768, 1024, 1024, 1024, 768, 0, 0, 0);
    gemm_bt_kernel<false, false><<<dim3(16, 6, 1), 256, 0, stream>>>(
        trgbf, WtT, t_key, b_t, 2048, 768, 1024, 1024, 1024, 768, 0, 0, 0);

    // 4. scores (fused rel_key, m256 pipelined), bf16
    scores_kernel<<<dim3(1, 64, 32), 512, 0, stream>>>(qh, s_key, t_key, scores);

    // 5. softmax in-place
    softmax_kernel<<<8192, 256, 0, stream>>>(scores);

    // 6. ctx (fused rel_key, m256 pipelined) -> xcat[:, 768:]
    ctx_kernel<<<dim3(1, 12, 32), 512, 0, stream>>>(scores, s_key, t_key, xcat);

    // 7. out = relu(xcat @ WoT^T + b_o)
    gemm_bt_kernel<false, true><<<dim3(64, 6, 1), 256, 0, stream>>>(
        xcat, WoT, d_out, b_o, 8192, 768, 1536, 1536, 1536, 768, 0, 0, 0);
}

// Round 13
// 449.988 us; speedup vs baseline: 1.1646x; 1.0080x over previous
//
#include <hip/hip_runtime.h>
#include <math.h>

// ---------------------------------------------------------------------------
// DynamicAttention4 (B=32 L=256 S=T=64 H=768 Q=768 F=1024 OUT=768)
// q=query@Wq+bq; s_key=src@Ws+bs; t_key=trg@Wt+bt
// rel_key[b,t,s,:]=tanh(s_key[b,s,:]+t_key[b,t,:])   (never materialized)
// scores[b,l,ts]=q·rel_key/sqrt(768); softmax over ts=4096
// ctx[b,l,:]=sum_ts w*rel_key; out=relu([query,ctx]@Wo+bo)
//
// Round-13 == round-10 resubmit (three GPU acquisition timeouts; no data).
// XCD-aware block swizzle for scores & ctx — all blocks of one batch land
// on one XCD (id%8 == b%8) so the shared A-operand (qh[b] / w[b]) is
// served from that XCD's L2 instead of re-fetched from HBM.
// ---------------------------------------------------------------------------

typedef __attribute__((ext_vector_type(8))) short bf16x8;
typedef __attribute__((ext_vector_type(4))) float f32x4;

__device__ __forceinline__ unsigned short f2bf(float f) {
    union { float f; unsigned u; } x; x.f = f;
    unsigned u = x.u;
    return (unsigned short)((u + 0x7fffu + ((u >> 16) & 1u)) >> 16);
}
__device__ __forceinline__ float bf2f(unsigned short h) {
    union { unsigned u; float f; } x; x.u = (unsigned)h << 16;
    return x.f;
}
__device__ __forceinline__ float tanh_fast(float x) {
    float e = __expf(2.0f * x);
    return 1.0f - 2.0f * __builtin_amdgcn_rcpf(1.0f + e);
}
__device__ __forceinline__ void async_copy16(void* lds, const void* g) {
    __builtin_amdgcn_global_load_lds(
        (const __attribute__((address_space(1))) unsigned int*)g,
        (__attribute__((address_space(3))) unsigned int*)lds,
        16, 0, 0);
}

// ---------------------------------------------------------------------------
// Batched bf16 BT-GEMM: C[z][m,n] = sum_k A[z][m,k]*BT[z][n,k] (+bias,+relu)
// 128x128 tile, BK=32, 4 waves, 4x4 16x16x32 frags. Same k-map for A/B.
// ---------------------------------------------------------------------------
template<bool OUT_BF16, bool RELU>
__global__ __launch_bounds__(256, 2) void gemm_bt_kernel(
    const unsigned short* __restrict__ A, const unsigned short* __restrict__ BT,
    void* __restrict__ Cout, const float* __restrict__ bias,
    int M, int N, int K, int lda, int ldb, int ldc,
    long long sA, long long sB, long long sC)
{
    __shared__ unsigned short As[128 * 32];
    __shared__ unsigned short Bs[128 * 32];
    const int z = blockIdx.z;
    A  += (long long)z * sA;
    BT += (long long)z * sB;
    const int m0 = blockIdx.x * 128, n0 = blockIdx.y * 128;
    const int tid = threadIdx.x;
    const int lane = tid & 63, wid = tid >> 6;
    const int wr = wid >> 1, wc = wid & 1;
    const int r = lane & 15, g = lane >> 4;

    f32x4 acc[4][4] = {};

    for (int k0 = 0; k0 < K; k0 += 32) {
        __syncthreads();
        #pragma unroll
        for (int j = 0; j < 2; ++j) {
            int c = j * 256 + tid;
            int row = c >> 2, kc = (c & 3) * 8;
            async_copy16(&As[c * 8], A  + (size_t)(m0 + row) * lda + k0 + kc);
            async_copy16(&Bs[c * 8], BT + (size_t)(n0 + row) * ldb + k0 + kc);
        }
        asm volatile("s_waitcnt vmcnt(0)" ::: "memory");
        __syncthreads();

        bf16x8 af[4], bfr[4];
        #pragma unroll
        for (int m = 0; m < 4; ++m)
            af[m] = *(const bf16x8*)&As[(wr * 64 + m * 16 + r) * 32 + g * 8];
        #pragma unroll
        for (int n = 0; n < 4; ++n)
            bfr[n] = *(const bf16x8*)&Bs[(wc * 64 + n * 16 + r) * 32 + g * 8];
        #pragma unroll
        for (int m = 0; m < 4; ++m)
            #pragma unroll
            for (int n = 0; n < 4; ++n)
                acc[m][n] = __builtin_amdgcn_mfma_f32_16x16x32_bf16(
                    af[m], bfr[n], acc[m][n], 0, 0, 0);
    }

    float* Cf = (float*)Cout;
    unsigned short* Cb = (unsigned short*)Cout;
    const long long cbase = (long long)z * sC;
    #pragma unroll
    for (int n = 0; n < 4; ++n) {
        int col = n0 + wc * 64 + n * 16 + r;
        float bv = bias ? bias[col] : 0.0f;
        #pragma unroll
        for (int m = 0; m < 4; ++m) {
            int row0 = m0 + wr * 64 + m * 16 + g * 4;
            #pragma unroll
            for (int i = 0; i < 4; ++i) {
                float v = acc[m][n][i] + bv;
                if (RELU) v = fmaxf(v, 0.0f);
                size_t off = (size_t)cbase + (size_t)(row0 + i) * ldc + col;
                if (OUT_BF16) Cb[off] = f2bf(v);
                else          Cf[off] = v;
            }
        }
    }
}

// ---------------------------------------------------------------------------
// scores[b,l,ts] fused GEMM, m256 x n64 (one t per block), 512 threads,
// 8 waves (4m x 2n), acc[4][2]. As(qh) double-buffered + prefetched.
// 1-D grid 2048, XCD-swizzled: id%8 == b%8 (same-batch blocks share L2).
// ---------------------------------------------------------------------------
__global__ __launch_bounds__(512, 4) void scores_kernel(
    const unsigned short* __restrict__ qh,   // [32][256][768]
    const float* __restrict__ s_key,         // [32][64][768]
    const float* __restrict__ t_key,         // [32][64][768]
    unsigned short* __restrict__ scores)     // [32][256][4096]
{
    __shared__ unsigned short As[2][256 * 32];   // 2 x 16 KB
    __shared__ unsigned short Bs[64 * 40];       // [s][k] stride 40

    // XCD swizzle: id = xcd + 8*(bi*64 + t), b = xcd + 8*bi
    const int id = blockIdx.x;
    const int xcd = id & 7, k = id >> 3;
    const int b = xcd + 8 * (k >> 6);
    const int t = k & 63;                        // ts window = t*64 .. +63

    const unsigned short* A = qh + (size_t)b * 256 * 768;
    const float* skp = s_key + (size_t)b * 64 * 768;
    const float* tkr = t_key + ((size_t)b * 64 + t) * 768;
    const int tid = threadIdx.x;
    const int lane = tid & 63, wid = tid >> 6;
    const int wr = wid >> 1, wc = wid & 1;       // 4m x 2n waves
    const int r = lane & 15, g = lane >> 4;
    const int sn = tid >> 3;                     // Bs row (s), 0..63
    const int kc4 = (tid & 7) * 4;               // 4 k-floats per thread

    auto stage = [&](int d, int k0) {
        #pragma unroll
        for (int j = 0; j < 2; ++j) {
            int c = j * 512 + tid;               // 1024 chunks (256 rows x 4)
            int row = c >> 2, kc = (c & 3) * 8;
            async_copy16(&As[d][c * 8], A + (size_t)row * 768 + k0 + kc);
        }
    };

    f32x4 acc[4][2] = {};

    stage(0, 0);
    asm volatile("s_waitcnt vmcnt(0)" ::: "memory");
    __syncthreads();

    for (int ks = 0; ks < 24; ++ks) {
        const int k0 = ks * 32, cur = ks & 1;

        // key loads for this k-window (issued before prefetch)
        float4 sv = *(const float4*)&skp[(size_t)sn * 768 + k0 + kc4];
        float4 tv = *(const float4*)&tkr[k0 + kc4];

        if (ks < 23) stage(cur ^ 1, k0 + 32);

        Bs[sn * 40 + kc4 + 0] = f2bf(tanh_fast(sv.x + tv.x));
        Bs[sn * 40 + kc4 + 1] = f2bf(tanh_fast(sv.y + tv.y));
        Bs[sn * 40 + kc4 + 2] = f2bf(tanh_fast(sv.z + tv.z));
        Bs[sn * 40 + kc4 + 3] = f2bf(tanh_fast(sv.w + tv.w));

        asm volatile("s_waitcnt lgkmcnt(0)" ::: "memory");
        __builtin_amdgcn_sched_barrier(0);
        __builtin_amdgcn_s_barrier();
        __builtin_amdgcn_sched_barrier(0);

        bf16x8 af[4], bfr[2];
        #pragma unroll
        for (int m = 0; m < 4; ++m)
            af[m] = *(const bf16x8*)&As[cur][(wr * 64 + m * 16 + r) * 32 + g * 8];
        #pragma unroll
        for (int n = 0; n < 2; ++n)
            bfr[n] = *(const bf16x8*)&Bs[(wc * 32 + n * 16 + r) * 40 + g * 8];
        #pragma unroll
        for (int m = 0; m < 4; ++m)
            #pragma unroll
            for (int n = 0; n < 2; ++n)
                acc[m][n] = __builtin_amdgcn_mfma_f32_16x16x32_bf16(
                    af[m], bfr[n], acc[m][n], 0, 0, 0);

        __syncthreads();   // drains prefetch; protects Bs/As reuse
    }

    unsigned short* C = scores + (size_t)b * 256 * 4096 + t * 64;
    #pragma unroll
    for (int n = 0; n < 2; ++n) {
        int col = wc * 32 + n * 16 + r;
        #pragma unroll
        for (int m = 0; m < 4; ++m) {
            int row0 = wr * 64 + m * 16 + g * 4;
            #pragma unroll
            for (int i = 0; i < 4; ++i)
                C[(size_t)(row0 + i) * 4096 + col] = f2bf(acc[m][n][i]);
        }
    }
}

// ---------------------------------------------------------------------------
// ctx[b,l,h] fused GEMM, m256 x n64, 512 threads, 8 waves (4m x 2n),
// acc[4][2]. BK=64 (one t per step, 64 steps). As double-buffered +
// prefetched + XOR-swizzled. 1-D grid 384, XCD-swizzled (id%8 == b%8).
// ---------------------------------------------------------------------------
__global__ __launch_bounds__(512, 4) void ctx_kernel(
    const unsigned short* __restrict__ w,    // [32][256][4096]
    const float* __restrict__ s_key,         // [32][64][768]
    const float* __restrict__ t_key,         // [32][64][768]
    unsigned short* __restrict__ xcat)       // [8192][1536]
{
    __shared__ unsigned short As[2][256 * 64];   // 2 x 32 KB, swizzled
    __shared__ unsigned short Bs[2][64 * 40];    // [kk][h][s] stride 40

    // XCD swizzle: id = xcd + 8*(bi*12 + n), b = xcd + 8*bi
    const int id = blockIdx.x;
    const int xcd = id & 7, k = id >> 3;         // k in [0,48)
    const int b = xcd + 8 * (k / 12);
    const int n0 = (k % 12) * 64;

    const unsigned short* A = w + (size_t)b * 256 * 4096;
    const float* skp = s_key + (size_t)b * 64 * 768;
    const float* tkp = t_key + (size_t)b * 64 * 768;
    const int tid = threadIdx.x;
    const int lane = tid & 63, wid = tid >> 6;
    const int wr = wid >> 1, wc = wid & 1;       // 4m x 2n waves
    const int r = lane & 15, g = lane >> 4;
    const int kkb = tid >> 8;                    // build: kk half (0/1)
    const int sl = tid & 31;                     // build: s within half
    const int hg = (tid >> 5) & 7;               // build: 8 h per thread

    auto stage = [&](int d, int t) {
        #pragma unroll
        for (int j = 0; j < 4; ++j) {
            int c = j * 512 + tid;               // 2048 chunks (256 rows x 8)
            int row = c >> 3, pcol = c & 7;
            int gcol = pcol ^ (row & 7);
            async_copy16(&As[d][c * 8],
                         A + (size_t)row * 4096 + t * 64 + gcol * 8);
        }
    };

    f32x4 acc[4][2] = {};

    stage(0, 0);
    asm volatile("s_waitcnt vmcnt(0)" ::: "memory");
    __syncthreads();

    for (int t = 0; t < 64; ++t) {
        const int cur = t & 1;

        // key loads for this t (consumed before prefetch completes)
        const float* tvp = &tkp[(size_t)t * 768 + n0 + hg * 8];
        const float* svp = &skp[(size_t)(kkb * 32 + sl) * 768 + n0 + hg * 8];
        float4 ta = *(const float4*)tvp, tb = *(const float4*)(tvp + 4);
        float4 sa = *(const float4*)svp, sb = *(const float4*)(svp + 4);

        if (t < 63) stage(cur ^ 1, t + 1);

        // build Bs[kkb][h][sl] = tanh(s_key + t_key), 8 h per thread
        {
            int hb = hg * 8;
            Bs[kkb][(hb + 0) * 40 + sl] = f2bf(tanh_fast(sa.x + ta.x));
            Bs[kkb][(hb + 1) * 40 + sl] = f2bf(tanh_fast(sa.y + ta.y));
            Bs[kkb][(hb + 2) * 40 + sl] = f2bf(tanh_fast(sa.z + ta.z));
            Bs[kkb][(hb + 3) * 40 + sl] = f2bf(tanh_fast(sa.w + ta.w));
            Bs[kkb][(hb + 4) * 40 + sl] = f2bf(tanh_fast(sb.x + tb.x));
            Bs[kkb][(hb + 5) * 40 + sl] = f2bf(tanh_fast(sb.y + tb.y));
            Bs[kkb][(hb + 6) * 40 + sl] = f2bf(tanh_fast(sb.z + tb.z));
            Bs[kkb][(hb + 7) * 40 + sl] = f2bf(tanh_fast(sb.w + tb.w));
        }

        // Bs-ready barrier WITHOUT vmcnt drain (prefetch stays in flight)
        asm volatile("s_waitcnt lgkmcnt(0)" ::: "memory");
        __builtin_amdgcn_sched_barrier(0);
        __builtin_amdgcn_s_barrier();
        __builtin_amdgcn_sched_barrier(0);

        #pragma unroll
        for (int kk = 0; kk < 2; ++kk) {
            bf16x8 af[4], bfr[2];
            #pragma unroll
            for (int m = 0; m < 4; ++m) {
                int rowr = wr * 64 + m * 16 + r;
                int phys = (kk * 4 + g) ^ (rowr & 7);
                af[m] = *(const bf16x8*)&As[cur][rowr * 64 + phys * 8];
            }
            #pragma unroll
            for (int n = 0; n < 2; ++n)
                bfr[n] = *(const bf16x8*)&Bs[kk][(wc * 32 + n * 16 + r) * 40 + g * 8];
            #pragma unroll
            for (int m = 0; m < 4; ++m)
                #pragma unroll
                for (int n = 0; n < 2; ++n)
                    acc[m][n] = __builtin_amdgcn_mfma_f32_16x16x32_bf16(
                        af[m], bfr[n], acc[m][n], 0, 0, 0);
        }

        __syncthreads();   // drains prefetch; protects As/Bs reuse
    }

    unsigned short* C = xcat + (size_t)b * 256 * 1536 + 768;
    #pragma unroll
    for (int n = 0; n < 2; ++n) {
        int col = n0 + wc * 32 + n * 16 + r;
        #pragma unroll
        for (int m = 0; m < 4; ++m) {
            int row0 = wr * 64 + m * 16 + g * 4;
            #pragma unroll
            for (int i = 0; i < 4; ++i)
                C[(size_t)(row0 + i) * 1536 + col] = f2bf(acc[m][n][i]);
        }
    }
}

// ---------------------------------------------------------------------------
// converters / transposes
// ---------------------------------------------------------------------------
__global__ void cvt_bf16_kernel(const float* __restrict__ in,
                                unsigned short* __restrict__ out, int n4) {
    int i = blockIdx.x * 256 + threadIdx.x;
    if (i >= n4) return;
    float4 v = ((const float4*)in)[i];
    ushort4 o;
    o.x = f2bf(v.x); o.y = f2bf(v.y); o.z = f2bf(v.z); o.w = f2bf(v.w);
    ((ushort4*)out)[i] = o;
}

__global__ void cvt_query_kernel(const float* __restrict__ in,
                                 unsigned short* __restrict__ xcat) {
    int i = blockIdx.x * 256 + threadIdx.x;
    if (i >= 8192 * 192) return;
    int row = i / 192, c4 = (i % 192) * 4;
    float4 v = ((const float4*)in)[i];
    ushort4 o;
    o.x = f2bf(v.x); o.y = f2bf(v.y); o.z = f2bf(v.z); o.w = f2bf(v.w);
    *(ushort4*)&xcat[(size_t)row * 1536 + c4] = o;
}

__global__ void transpose_w_kernel(const float* __restrict__ in,
                                   unsigned short* __restrict__ out,
                                   int R, int C) {
    __shared__ float tile[64][65];
    const int r0 = blockIdx.y * 64, c0 = blockIdx.x * 64;
    const int tx = threadIdx.x & 63, ty = threadIdx.x >> 6;
    for (int i = ty; i < 64; i += 4)
        tile[i][tx] = in[(size_t)(r0 + i) * C + c0 + tx];
    __syncthreads();
    for (int i = ty; i < 64; i += 4)
        out[(size_t)(c0 + i) * R + r0 + tx] = f2bf(tile[tx][i]);
}

// ---------------------------------------------------------------------------
// row softmax over 4096 (bf16 in-place), scale 1/sqrt(768) before exp
// ---------------------------------------------------------------------------
__global__ __launch_bounds__(256) void softmax_kernel(unsigned short* __restrict__ scores) {
    unsigned short* p = scores + (size_t)blockIdx.x * 4096;
    const int tid = threadIdx.x, lane = tid & 63, wid = tid >> 6;
    __shared__ float red[4];

    float v[16];
    {
        const bf16x8* p8 = (const bf16x8*)p;
        bf16x8 a = p8[tid * 2], c = p8[tid * 2 + 1];
        #pragma unroll
        for (int e = 0; e < 8; ++e) {
            v[e]     = bf2f((unsigned short)a[e]);
            v[8 + e] = bf2f((unsigned short)c[e]);
        }
    }
    float mx = v[0];
    #pragma unroll
    for (int e = 1; e < 16; ++e) mx = fmaxf(mx, v[e]);
    #pragma unroll
    for (int o = 32; o; o >>= 1) mx = fmaxf(mx, __shfl_xor(mx, o));
    if (lane == 0) red[wid] = mx;
    __syncthreads();
    mx = fmaxf(fmaxf(red[0], red[1]), fmaxf(red[2], red[3]));
    __syncthreads();

    const float scale = 0.03608439182435161f;   // 1/sqrt(768)
    float sum = 0.0f;
    #pragma unroll
    for (int e = 0; e < 16; ++e) {
        v[e] = __expf((v[e] - mx) * scale);
        sum += v[e];
    }
    #pragma unroll
    for (int o = 32; o; o >>= 1) sum += __shfl_xor(sum, o);
    if (lane == 0) red[wid] = sum;
    __syncthreads();
    sum = red[0] + red[1] + red[2] + red[3];
    const float inv = 1.0f / sum;

    bf16x8* p8 = (bf16x8*)p;
    #pragma unroll
    for (int j = 0; j < 2; ++j) {
        bf16x8 o;
        #pragma unroll
        for (int e = 0; e < 8; ++e)
            o[e] = (short)f2bf(v[j * 8 + e] * inv);
        p8[tid * 2 + j] = o;
    }
}

// ---------------------------------------------------------------------------
extern "C" void kernel_launch(void* const* d_in, const int* in_sizes, int n_in,
                              void* d_out, int out_size, void* d_ws, size_t ws_size,
                              hipStream_t stream) {
    const float* query = (const float*)d_in[0];
    const float* src   = (const float*)d_in[1];
    const float* trg   = (const float*)d_in[2];
    const float* Wq    = (const float*)d_in[3];
    const float* b_q   = (const float*)d_in[4];
    const float* Ws    = (const float*)d_in[5];
    const float* b_s   = (const float*)d_in[6];
    const float* Wt    = (const float*)d_in[7];
    const float* b_t   = (const float*)d_in[8];
    const float* Wo    = (const float*)d_in[9];
    const float* b_o   = (const float*)d_in[10];

    char* ws = (char*)d_ws;
    size_t off = 0;
    auto alloc = [&](size_t bytes) {
        void* p = ws + off;
        off += (bytes + 255) & ~(size_t)255;
        return p;
    };
    unsigned short* xcat   = (unsigned short*)alloc((size_t)8192 * 1536 * 2);
    unsigned short* srcbf  = (unsigned short*)alloc((size_t)2048 * 1024 * 2);
    unsigned short* trgbf  = (unsigned short*)alloc((size_t)2048 * 1024 * 2);
    unsigned short* WqT    = (unsigned short*)alloc((size_t)768 * 768 * 2);
    unsigned short* WsT    = (unsigned short*)alloc((size_t)768 * 1024 * 2);
    unsigned short* WtT    = (unsigned short*)alloc((size_t)768 * 1024 * 2);
    unsigned short* WoT    = (unsigned short*)alloc((size_t)768 * 1536 * 2);
    unsigned short* qh     = (unsigned short*)alloc((size_t)8192 * 768 * 2);
    float*          s_key  = (float*)alloc((size_t)2048 * 768 * 4);
    float*          t_key  = (float*)alloc((size_t)2048 * 768 * 4);
    unsigned short* scores = (unsigned short*)alloc((size_t)32 * 256 * 4096 * 2);
    // total ~133 MB (known-safe)

    // 1. input converts
    cvt_query_kernel<<<6144, 256, 0, stream>>>(query, xcat);
    cvt_bf16_kernel<<<2048, 256, 0, stream>>>(src, srcbf, 524288);
    cvt_bf16_kernel<<<2048, 256, 0, stream>>>(trg, trgbf, 524288);

    // 2. weight transposes
    transpose_w_kernel<<<dim3(12, 12), 256, 0, stream>>>(Wq, WqT, 768, 768);
    transpose_w_kernel<<<dim3(12, 16), 256, 0, stream>>>(Ws, WsT, 1024, 768);
    transpose_w_kernel<<<dim3(12, 16), 256, 0, stream>>>(Wt, WtT, 1024, 768);
    transpose_w_kernel<<<dim3(12, 24), 256, 0, stream>>>(Wo, WoT, 1536, 768);

    // 3. projections
    gemm_bt_kernel<true, false><<<dim3(64, 6, 1), 256, 0, stream>>>(
        xcat, WqT, qh, b_q, 8192, 768, 768, 1536, 768, 768, 0, 0, 0);
    gemm_bt_kernel<false, false><<<dim3(16, 6, 1), 256, 0, stream>>>(
        srcbf, WsT, s_key, b_s, 2048, 768, 1024, 1024, 1024, 768, 0, 0, 0);
    gemm_bt_kernel<false, false><<<dim3(16, 6, 1), 256, 0, stream>>>(
        trgbf, WtT, t_key, b_t, 2048, 768, 1024, 1024, 1024, 768, 0, 0, 0);

    // 4. scores (fused rel_key, m256 pipelined, XCD-swizzled), bf16
    scores_kernel<<<2048, 512, 0, stream>>>(qh, s_key, t_key, scores);

    // 5. softmax in-place
    softmax_kernel<<<8192, 256, 0, stream>>>(scores);

    // 6. ctx (fused rel_key, m256 pipelined, XCD-swizzled) -> xcat[:, 768:]
    ctx_kernel<<<384, 512, 0, stream>>>(scores, s_key, t_key, xcat);

    // 7. out = relu(xcat @ WoT^T + b_o)
    gemm_bt_kernel<false, true><<<dim3(64, 6, 1), 256, 0, stream>>>(
        xcat, WoT, d_out, b_o, 8192, 768, 1536, 1536, 1536, 768, 0, 0, 0);
}